// Round 21
// baseline (47.189 us; speedup 1.0000x reference)
//
#include <hip/hip_runtime.h>
#include <hip/hip_bf16.h>

// Problem constants
#define NF  200
#define DIN 3
#define NH  15
#define NE  30
#define NB  32768

typedef __attribute__((ext_vector_type(8)))  short short8;
typedef __attribute__((ext_vector_type(16))) float f32x16;

constexpr int FSPLIT = 25;           // feature split across grid.y
constexpr int FPW    = NF / FSPLIT;  // 8 features per block-slice -> 4 pairs
constexpr int PAIRS  = FPW / 2;      // 4
constexpr int BT     = 256;          // threads per block (4 waves)
constexpr int RPW    = 32;           // rows per wave (one 32x32 MFMA tile)
constexpr int RPB    = 4 * RPW;      // 128 rows per block -> grid.x = 256

// ws layout:
// A1P : [100][64][8 bf16] pair-packed layer-1 A-frag            @ 0       (102400 B)
// W2Q : [200][64][8 bf16] layer-2 W2 fragment (lane=e, k=perm'd h, b2@k15)
//                                                                @ 102400  (204800 B)
// W3B : [200][2(eh)][2(hi)][8] bf16  W3 epilogue B-fragments:
//        value = W3[eh*16 + crow(j,hi)], e>=30 -> 0              @ 307200  (12800 B)
// P   : [25][32768] f32 partials (fully rewritten each call)    @ 320000  (3276800 B)
constexpr size_t OFF_A1P = 0;
constexpr size_t OFF_W2Q = 102400;
constexpr size_t OFF_W3B = 307200;
constexpr size_t OFF_P   = 320000;

__device__ __forceinline__ unsigned f2bfu(float x) {
    __hip_bfloat16 h = __float2bfloat16(x);
    unsigned short u; __builtin_memcpy(&u, &h, 2); return (unsigned)u;
}

// HW packed convert: lo -> D[15:0], hi -> D[31:16], RNE (same as __float2bfloat16)
__device__ __forceinline__ unsigned cvtpk(float lo, float hi) {
    unsigned r;
    asm("v_cvt_pk_bf16_f32 %0, %1, %2" : "=v"(r) : "v"(lo), "v"(hi));
    return r;
}

__global__ void nn_prep(const float* __restrict__ W1, const float* __restrict__ b1,
                        const float* __restrict__ W2, const float* __restrict__ b2,
                        const float* __restrict__ W3, char* __restrict__ ws) {
    const int f = blockIdx.x;
    const int t = threadIdx.x;      // 64
    const int x = t & 31, hi = t >> 5;
    unsigned short* A1p = (unsigned short*)(ws + OFF_A1P);
    unsigned short* W2q = (unsigned short*)(ws + OFF_W2Q);
    unsigned short* w3b = (unsigned short*)(ws + OFF_W3B);

    // ---- W2 fragment (lane=e, k-slots=perm'd h); h==15 slot carries b2 ----
    {
        unsigned short* d = W2q + ((size_t)f * 64 + t) * 8;
#pragma unroll
        for (int j = 0; j < 8; ++j) {
            const int h = (j & 3) + 8 * (j >> 2) + 4 * hi;   // 0..15
            float v = 0.f;
            if (x < NE) v = (h < NH) ? W2[((size_t)f * NH + h) * NE + x]
                                     : b2[f * NE + x];       // h==15
            d[j] = (unsigned short)f2bfu(v);
        }
    }
    // ---- W3 epilogue B-fragments: [f][eh][hh][j] = W3[eh*16+crow(j,hh)] ----
    if (t < 32) {
        const int eh = t >> 4, hh = (t >> 3) & 1, j = t & 7;
        const int e  = eh * 16 + (j & 3) + 8 * (j >> 2) + 4 * hh;
        w3b[(size_t)f * 32 + t] =
            (e < NE) ? (unsigned short)f2bfu(W3[f * NE + e]) : (unsigned short)0;
    }

    // ---- pair-packed layer-1 A fragment (even f writes pair f/2) ----
    if ((f & 1) == 0) {
        unsigned short* a = A1p + ((size_t)(f >> 1) * 64 + t) * 8;
#pragma unroll
        for (int j = 0; j < 8; ++j) {
            float v = 0.f;
            if (hi == 0) {
                if (x < 16) {                    // feature f, h = x, k0-3
                    if (x < NH) {
                        if (j < 3)       v = W1[((size_t)f * DIN + j) * NH + x];
                        else if (j == 3) v = b1[f * NH + x];
                    }
                } else {                          // feature f+1, h = x-16, k4-7
                    const int h = x - 16;
                    if (h < NH) {
                        if (j >= 4 && j < 7) v = W1[((size_t)(f + 1) * DIN + (j - 4)) * NH + h];
                        else if (j == 7)     v = b1[(f + 1) * NH + h];
                    }
                }
            }
            a[j] = (unsigned short)f2bfu(v);
        }
    }
}

__global__ __launch_bounds__(BT, 3)
void nn_main(const float* __restrict__ y, const char* __restrict__ ws,
             float* __restrict__ P) {
    // LDS-staged per-block weight slice -- 12.8 KB total
    __shared__ __align__(16) short sA1[PAIRS * 512];   //  4096 B = 256 uint4
    __shared__ __align__(16) short sW2[FPW * 512];     //  8192 B = 512 uint4
    __shared__ __align__(16) short sW3B[FPW * 32];     //   512 B =  32 uint4

    const int t  = threadIdx.x;
    const int w  = t >> 6;
    const int l  = t & 63;
    const int ln = l & 31;
    const int hi = l >> 5;
    const int r0 = blockIdx.x * RPB + w * RPW;
    const int f0 = blockIdx.y * FPW;
    const int p0 = f0 >> 1;

    // ---- issue ALL y loads first (independent of LDS staging / barrier) ----
    const float4* __restrict__ yp4 = reinterpret_cast<const float4*>(
        y + (size_t)(r0 + ln) * (NF * DIN) + (size_t)f0 * DIN);
    const float4 c0 = yp4[0], c1 = yp4[1], c2 = yp4[2];
    const float4 c3 = yp4[3], c4 = yp4[4], c5 = yp4[5];

    // ---- stage weights global -> LDS (coalesced uint4 copies, BT=256) ----
    {
        const uint4* gA = (const uint4*)(ws + OFF_A1P + (size_t)p0 * 1024);
        const uint4* gW = (const uint4*)(ws + OFF_W2Q + (size_t)f0 * 1024);
        const uint4* g3 = (const uint4*)(ws + OFF_W3B + (size_t)f0 * 64);
        uint4* dA = (uint4*)sA1;
        uint4* dW = (uint4*)sW2;
        uint4* d3 = (uint4*)sW3B;
        dA[t] = gA[t];                 // 256 uint4
        dW[t]       = gW[t];           // 512 uint4
        dW[t + 256] = gW[t + 256];
        if (t < 32) d3[t] = g3[t];     // 32 uint4
    }
    __syncthreads();

    const short* __restrict__ a1l = sA1 + l * 8;
    const short* __restrict__ w2l = sW2 + l * 8;

    const unsigned himask = hi ? 0x3F800000u : 0u;   // bf16(1.0) @ k15 for hi lanes
    const float onef = 1.0f;
    const f32x16 zc = {};

    f32x16 accL = {};   // e 0..15  (both hi-halves enter via k-slots)
    f32x16 accH = {};   // e 16..31

    auto pair_body = [&](int pp, float y0A, float y1A, float y2A,
                                 float y0B, float y1B, float y2B) {
        const short8 A1  = *reinterpret_cast<const short8*>(a1l + (size_t)pp * 512);
        const short8 W2A = *reinterpret_cast<const short8*>(w2l + (size_t)(2 * pp) * 512);
        const short8 W2B = *reinterpret_cast<const short8*>(w2l + (size_t)(2 * pp + 1) * 512);
        const short8 W3A0 = *reinterpret_cast<const short8*>(sW3B + (2 * pp) * 32 + hi * 8);
        const short8 W3A1 = *reinterpret_cast<const short8*>(sW3B + (2 * pp) * 32 + 16 + hi * 8);
        const short8 W3B0 = *reinterpret_cast<const short8*>(sW3B + (2 * pp + 1) * 32 + hi * 8);
        const short8 W3B1 = *reinterpret_cast<const short8*>(sW3B + (2 * pp + 1) * 32 + 16 + hi * 8);

        // B1: k0-2 = y_A, k3 = 1, k4-6 = y_B, k7 = 1
        union { unsigned u[4]; short8 s; } B1;
        B1.u[0] = cvtpk(y0A, y1A);
        B1.u[1] = cvtpk(y2A, onef);
        B1.u[2] = cvtpk(y0B, y1B);
        B1.u[3] = cvtpk(y2B, onef);

        // layer 1: d1[h][brow]
        const f32x16 d1 = __builtin_amdgcn_mfma_f32_32x32x16_bf16(A1, B1.s, zc, 0, 0, 0);

        // pack relu(h1) as layer-2 B-operand; 1.0 @ k15 multiplies the b2 row
        union { unsigned u[4]; short8 s; } PA, PB;
#pragma unroll
        for (int i = 0; i < 4; ++i) {
            PA.u[i] = cvtpk(fmaxf(d1[2 * i], 0.f),     fmaxf(d1[2 * i + 1], 0.f));
            PB.u[i] = cvtpk(fmaxf(d1[8 + 2 * i], 0.f), fmaxf(d1[8 + 2 * i + 1], 0.f));
        }
        PA.u[3] |= himask;
        PB.u[3] |= himask;

        // layer 2 TRANSPOSED: d2t[e][brow]; then layer-3 dot on the MATRIX pipe:
        // acc = mfma(pack(relu(d2t)), W3frag, acc) -- D regs = sum_e relu*W3 per brow
        {
            const f32x16 d2 = __builtin_amdgcn_mfma_f32_32x32x16_bf16(W2A, PA.s, zc, 0, 0, 0);
            union { unsigned u[4]; short8 s; } RL, RH;
#pragma unroll
            for (int i = 0; i < 4; ++i) {
                RL.u[i] = cvtpk(fmaxf(d2[2 * i], 0.f),     fmaxf(d2[2 * i + 1], 0.f));
                RH.u[i] = cvtpk(fmaxf(d2[8 + 2 * i], 0.f), fmaxf(d2[8 + 2 * i + 1], 0.f));
            }
            accL = __builtin_amdgcn_mfma_f32_32x32x16_bf16(RL.s, W3A0, accL, 0, 0, 0);
            accH = __builtin_amdgcn_mfma_f32_32x32x16_bf16(RH.s, W3A1, accH, 0, 0, 0);
        }
        {
            const f32x16 d2 = __builtin_amdgcn_mfma_f32_32x32x16_bf16(W2B, PB.s, zc, 0, 0, 0);
            union { unsigned u[4]; short8 s; } RL, RH;
#pragma unroll
            for (int i = 0; i < 4; ++i) {
                RL.u[i] = cvtpk(fmaxf(d2[2 * i], 0.f),     fmaxf(d2[2 * i + 1], 0.f));
                RH.u[i] = cvtpk(fmaxf(d2[8 + 2 * i], 0.f), fmaxf(d2[8 + 2 * i + 1], 0.f));
            }
            accL = __builtin_amdgcn_mfma_f32_32x32x16_bf16(RL.s, W3B0, accL, 0, 0, 0);
            accH = __builtin_amdgcn_mfma_f32_32x32x16_bf16(RH.s, W3B1, accH, 0, 0, 0);
        }
    };

    pair_body(0, c0.x, c0.y, c0.z,  c0.w, c1.x, c1.y);
    pair_body(1, c1.z, c1.w, c2.x,  c2.y, c2.z, c2.w);
    pair_body(2, c3.x, c3.y, c3.z,  c3.w, c4.x, c4.y);
    pair_body(3, c4.z, c4.w, c5.x,  c5.y, c5.z, c5.w);

    // ---- D already summed over e (k spans both hi-halves); identical across cols.
    //      reg r of lane(hi) holds row crow(r,hi). Store once per row from ln==0.
    float pr[16];
#pragma unroll
    for (int r = 0; r < 16; ++r) pr[r] = accL[r] + accH[r];
    if (ln == 0) {
#pragma unroll
        for (int r = 0; r < 16; ++r) {
            const int row = (r & 3) + 8 * (r >> 2) + 4 * hi;
            P[(size_t)blockIdx.y * NB + r0 + row] = pr[r];
        }
    }
}

// ---------------- reduce kernel: out[i] = b3 + sum_s P[s][i] ----------------
__global__ __launch_bounds__(256)
void nn_reduce(const float* __restrict__ P, const float* __restrict__ b3,
               float* __restrict__ out) {
    const int i = blockIdx.x * 256 + threadIdx.x;
    float s = b3[0];
#pragma unroll
    for (int k = 0; k < FSPLIT; ++k) s += P[(size_t)k * NB + i];
    out[i] = s;
}

extern "C" void kernel_launch(void* const* d_in, const int* in_sizes, int n_in,
                              void* d_out, int out_size, void* d_ws, size_t ws_size,
                              hipStream_t stream) {
    const float* y  = (const float*)d_in[0];
    const float* W1 = (const float*)d_in[1];
    const float* b1 = (const float*)d_in[2];
    const float* W2 = (const float*)d_in[3];
    const float* b2 = (const float*)d_in[4];
    const float* W3 = (const float*)d_in[5];
    const float* b3 = (const float*)d_in[6];
    float* out = (float*)d_out;
    char*  ws  = (char*)d_ws;
    float* P   = (float*)(ws + OFF_P);   // fully rewritten each call

    nn_prep<<<dim3(NF), dim3(64), 0, stream>>>(W1, b1, W2, b2, W3, ws);
    nn_main<<<dim3(NB / RPB, FSPLIT), dim3(BT), 0, stream>>>(
        y, (const char*)ws, P);
    nn_reduce<<<dim3(NB / 256), dim3(256), 0, stream>>>(P, b3, out);
}